// Round 1
// baseline (2871.432 us; speedup 1.0000x reference)
//
#include <hip/hip_runtime.h>
#include <hip/hip_bf16.h>
#include <stdint.h>
#include <stddef.h>

// Problem constants
#define B_ 32
#define T_ 32
#define S_ 128
#define H_ 512
#define V_ 50257
#define VPAD 50304
#define TH3 1536   // 3*H

typedef __attribute__((ext_vector_type(8))) short short8x;
typedef __attribute__((ext_vector_type(4))) float f32x4;

__device__ __forceinline__ float sigf(float x) { return 1.f / (1.f + __expf(-x)); }
__device__ __forceinline__ float tanhfast(float x) {
  float e = __expf(2.f * x);
  return 1.f - 2.f / (e + 1.f);
}
__device__ __forceinline__ unsigned short f2bf(float x) {
  unsigned int u = __float_as_uint(x);
  return (unsigned short)((u + 0x7fffu + ((u >> 16) & 1u)) >> 16);
}
__device__ __forceinline__ float dot4(float4 a, float4 b) {
  return a.x * b.x + a.y * b.y + a.z * b.z + a.w * b.w;
}

__device__ __forceinline__ void async16(const unsigned short* g, short* l) {
  __builtin_amdgcn_global_load_lds(
      (const __attribute__((address_space(1))) unsigned int*)g,
      (__attribute__((address_space(3))) unsigned int*)l, 16, 0, 0);
}

// ---------------- hierarchical grid barrier (256 blocks) ----------------
// bar region: 4096 B zeroed by hipMemsetAsync each call.
// counters: c1[grp] at bar[grp*32] (8 groups of 32 blocks), level2 at bar[448], gen at bar[512]
__device__ __forceinline__ void gridbar(int* bar) {
  __syncthreads();
  if (threadIdx.x == 0) {
    int* gen = bar + 512;
    int g = __hip_atomic_load(gen, __ATOMIC_RELAXED, __HIP_MEMORY_SCOPE_AGENT);
    int* c1 = bar + ((blockIdx.x >> 5) << 5);
    int a = __hip_atomic_fetch_add(c1, 1, __ATOMIC_ACQ_REL, __HIP_MEMORY_SCOPE_AGENT);
    bool done = false;
    if (a == 31) {
      __hip_atomic_store(c1, 0, __ATOMIC_RELAXED, __HIP_MEMORY_SCOPE_AGENT);
      int a2 = __hip_atomic_fetch_add(bar + 448, 1, __ATOMIC_ACQ_REL, __HIP_MEMORY_SCOPE_AGENT);
      if (a2 == 7) {
        __hip_atomic_store(bar + 448, 0, __ATOMIC_RELAXED, __HIP_MEMORY_SCOPE_AGENT);
        __hip_atomic_fetch_add(gen, 1, __ATOMIC_RELEASE, __HIP_MEMORY_SCOPE_AGENT);
        done = true;
      }
    }
    if (!done) {
      while (__hip_atomic_load(gen, __ATOMIC_RELAXED, __HIP_MEMORY_SCOPE_AGENT) == g)
        __builtin_amdgcn_s_sleep(1);
      __builtin_amdgcn_fence(__ATOMIC_ACQUIRE, "agent");
    }
  }
  __syncthreads();
}

// one gh0-style dot: o = b*1536 + j; gh0v[o] = dot(h[b,:], Whh0[j,:]) + bhh0[j]
__device__ __forceinline__ void gh0_one(int o, const float* __restrict__ hbase,
                                        const float* __restrict__ Whh0,
                                        const float* __restrict__ bhh0,
                                        float* __restrict__ gh0v) {
  const int b = o / 1536;
  const int j = o - b * 1536;
  const float* a = hbase + (size_t)b * 512;
  const float* w = Whh0 + (size_t)j * 512;
  float acc = 0.f;
#pragma unroll 4
  for (int k = 0; k < 512; k += 4)
    acc += dot4(*(const float4*)(a + k), *(const float4*)(w + k));
  gh0v[o] = acc + bhh0[j];
}

// ---------------- Ws fp32 -> bf16 (padded to VPAD, pad rows zero) ----------------
__global__ __launch_bounds__(256) void cvt_kernel(const float* __restrict__ Ws,
                                                  unsigned short* __restrict__ outb) {
  size_t i = ((size_t)blockIdx.x * 256 + threadIdx.x) * 4;
  if (i >= (size_t)VPAD * 512) return;
  float4 f;
  if (i < (size_t)V_ * 512) f = *(const float4*)(Ws + i);
  else f = make_float4(0.f, 0.f, 0.f, 0.f);
  ushort4 u;
  u.x = f2bf(f.x); u.y = f2bf(f.y); u.z = f2bf(f.z); u.w = f2bf(f.w);
  *(ushort4*)(outb + i) = u;
}

// ---------------- generic fp32 tiled GEMM: C[M,N] = A[M,512] * Bw[N,512]^T + bias ----
// MODE 0: A row m -> emb_W[token(m)], token(m): t=m>>5,b=m&31, tok = t==0 ? 1 : tgt[b*32+t-1]
// MODE 1: A row m -> enc_out[(s*32+b)*512] with b=m>>7, s=m&127
template <int MODE>
__global__ __launch_bounds__(256) void gemm_f32(const float* __restrict__ Asrc,
                                                const float* __restrict__ Bw,
                                                const float* __restrict__ bias,
                                                float* __restrict__ Cout,
                                                const int* __restrict__ tgt, int N) {
  __shared__ __align__(16) float As[16][68];
  __shared__ __align__(16) float Bs[16][68];
  const int tid = threadIdx.x;
  const int tx = tid & 15, ty = tid >> 4;
  const int m0 = blockIdx.y * 64, n0 = blockIdx.x * 64;
  const int srow = tid >> 2, skq = (tid & 3) * 4;
  const float* arow;
  {
    int m = m0 + srow;
    if (MODE == 0) {
      int t = m >> 5, b = m & 31;
      int tok = (t == 0) ? 1 : tgt[b * 32 + t - 1];
      arow = Asrc + (size_t)tok * 512;
    } else {
      int b = m >> 7, s = m & 127;
      arow = Asrc + ((size_t)s * 32 + b) * 512;
    }
  }
  const float* brow = Bw + (size_t)(n0 + srow) * 512;
  float acc[4][4] = {};
  for (int k0 = 0; k0 < 512; k0 += 16) {
    float4 av = *(const float4*)(arow + k0 + skq);
    float4 bv = *(const float4*)(brow + k0 + skq);
    __syncthreads();
    As[skq + 0][srow] = av.x; As[skq + 1][srow] = av.y;
    As[skq + 2][srow] = av.z; As[skq + 3][srow] = av.w;
    Bs[skq + 0][srow] = bv.x; Bs[skq + 1][srow] = bv.y;
    Bs[skq + 2][srow] = bv.z; Bs[skq + 3][srow] = bv.w;
    __syncthreads();
#pragma unroll
    for (int kk = 0; kk < 16; ++kk) {
      float4 a4 = *(const float4*)&As[kk][ty * 4];
      float4 b4 = *(const float4*)&Bs[kk][tx * 4];
      acc[0][0] += a4.x * b4.x; acc[0][1] += a4.x * b4.y; acc[0][2] += a4.x * b4.z; acc[0][3] += a4.x * b4.w;
      acc[1][0] += a4.y * b4.x; acc[1][1] += a4.y * b4.y; acc[1][2] += a4.y * b4.z; acc[1][3] += a4.y * b4.w;
      acc[2][0] += a4.z * b4.x; acc[2][1] += a4.z * b4.y; acc[2][2] += a4.z * b4.z; acc[2][3] += a4.z * b4.w;
      acc[3][0] += a4.w * b4.x; acc[3][1] += a4.w * b4.y; acc[3][2] += a4.w * b4.z; acc[3][3] += a4.w * b4.w;
    }
  }
  float4 b4 = *(const float4*)(bias + n0 + tx * 4);
#pragma unroll
  for (int i = 0; i < 4; ++i) {
    float4 o;
    o.x = acc[i][0] + b4.x; o.y = acc[i][1] + b4.y;
    o.z = acc[i][2] + b4.z; o.w = acc[i][3] + b4.w;
    *(float4*)(Cout + (size_t)(m0 + ty * 4 + i) * N + n0 + tx * 4) = o;
  }
}

// ---------------- persistent sequential kernel: 32 GRU+attention steps ----------------
__global__ __launch_bounds__(256, 2) void seq_kernel(
    const float* __restrict__ dh, const float* __restrict__ enc,
    const unsigned char* __restrict__ mask,
    const float* __restrict__ Whh, const float* __restrict__ Wih,
    const float* __restrict__ bih, const float* __restrict__ bhh,
    const float* __restrict__ Wc, const float* __restrict__ bc,
    int* __restrict__ bar, float* __restrict__ h0b, float* __restrict__ h1b,
    float* __restrict__ gh0v, float* __restrict__ gx1v, float* __restrict__ gh1v,
    const float* __restrict__ gx0v, const float* __restrict__ encp,
    unsigned short* __restrict__ cbf, float* __restrict__ out_hf) {
  const int tid = threadIdx.x, bid = blockIdx.x;
  __shared__ __align__(16) float sm[2048];

  // ---- phase 0: copy initial hidden state + gh0 for t=0 ----
  {
    int gt = bid * 256 + tid;
    if (gt < 16384) h0b[gt] = dh[gt];
    else if (gt < 32768) h1b[gt - 16384] = dh[gt];
    if (gt < 49152) gh0_one(gt, dh, Whh, bhh, gh0v);  // layer0 init = dh[0..16384)
  }
  gridbar(bar);

  for (int t = 0; t < 32; ++t) {
    const int cur = t & 1, nxt = cur ^ 1;

    // ================= phase B: cell0 (recompute) + gx1, gh1 =================
    if (bid < 96) {
      // gx1 blocks: 8 b-groups x 12 j-groups
      const int bg = bid & 7, jg = bid >> 3;
      for (int i = tid; i < 2048; i += 256) {
        const int bs_ = i >> 9, ii = i & 511;
        const int b = bg * 4 + bs_;
        const float* gx = gx0v + ((size_t)t * 32 + b) * 1536;
        const float* gh = gh0v + (size_t)b * 1536;
        const float hv = h0b[cur * 16384 + b * 512 + ii];
        const float r = sigf(gx[ii] + gh[ii]);
        const float z = sigf(gx[512 + ii] + gh[512 + ii]);
        const float n = tanhfast(gx[1024 + ii] + r * gh[1024 + ii]);
        const float x = (1.f - z) * n + z * hv;
        sm[i] = x;
        if (jg == 0) h0b[nxt * 16384 + b * 512 + ii] = x;
      }
      __syncthreads();
      const int jj = tid & 127, bs_ = tid >> 7;
      const int j = jg * 128 + jj;
      const float* wrow = Wih + (size_t)TH3 * 512 + (size_t)j * 512;  // layer 1
      const float* xA = sm + bs_ * 512;
      const float* xB = sm + (bs_ + 2) * 512;
      float a0 = 0.f, a1 = 0.f;
#pragma unroll 4
      for (int k = 0; k < 512; k += 4) {
        float4 w4 = *(const float4*)(wrow + k);
        a0 += dot4(*(const float4*)(xA + k), w4);
        a1 += dot4(*(const float4*)(xB + k), w4);
      }
      const float bb = bih[TH3 + j];
      gx1v[(size_t)(bg * 4 + bs_) * 1536 + j] = a0 + bb;
      gx1v[(size_t)(bg * 4 + bs_ + 2) * 1536 + j] = a1 + bb;
    } else if (bid < 192) {
      // gh1 blocks
      const int b2 = bid - 96;
      const int bg = b2 & 7, jg = b2 >> 3;
      const int jj = tid & 127, bs_ = tid >> 7;
      const int j = jg * 128 + jj;
      const float* wrow = Whh + (size_t)TH3 * 512 + (size_t)j * 512;  // layer 1
      const float* xA = h1b + cur * 16384 + (size_t)(bg * 4 + bs_) * 512;
      const float* xB = xA + 1024;
      float a0 = 0.f, a1 = 0.f;
#pragma unroll 4
      for (int k = 0; k < 512; k += 4) {
        float4 w4 = *(const float4*)(wrow + k);
        a0 += dot4(*(const float4*)(xA + k), w4);
        a1 += dot4(*(const float4*)(xB + k), w4);
      }
      const float bb = bhh[TH3 + j];
      gh1v[(size_t)(bg * 4 + bs_) * 1536 + j] = a0 + bb;
      gh1v[(size_t)(bg * 4 + bs_ + 2) * 1536 + j] = a1 + bb;
    }
    gridbar(bar);

    // ============ phase C: attention/concat (128 blk) || next gh0 (128 blk) ============
    if (bid < 128) {
      const int b = bid >> 2, q = bid & 3;
      float* X = sm;            // 512
      float* CTX = sm + 512;    // 512
      float* SC = sm + 1024;    // 128
      float* AT = sm + 1152;    // 128
      float* PART = sm + 1280;  // 256
      // cell1 recompute -> x (= new h1)
      for (int i = tid; i < 512; i += 256) {
        const float* gx = gx1v + (size_t)b * 1536;
        const float* gh = gh1v + (size_t)b * 1536;
        const float hv = h1b[cur * 16384 + b * 512 + i];
        const float r = sigf(gx[i] + gh[i]);
        const float z = sigf(gx[512 + i] + gh[512 + i]);
        const float n = tanhfast(gx[1024 + i] + r * gh[1024 + i]);
        const float x = (1.f - z) * n + z * hv;
        X[i] = x;
        if (q == 0) h1b[nxt * 16384 + b * 512 + i] = x;
        if (q == 1 && t == 31) out_hf[16384 + b * 512 + i] = x;
      }
      __syncthreads();
      // scores: 2 threads per s (k-split)
      {
        const int s = tid >> 1, kh = tid & 1;
        const float* ep = encp + ((size_t)b * 128 + s) * 512 + kh * 256;
        const float* xx = X + kh * 256;
        float a = 0.f;
#pragma unroll 4
        for (int k = 0; k < 256; k += 4)
          a += dot4(*(const float4*)(ep + k), *(const float4*)(xx + k));
        PART[tid] = a;
      }
      __syncthreads();
      if (tid < 128) {
        float sc = PART[2 * tid] + PART[2 * tid + 1];
        if (mask[b * 128 + tid]) sc = -1e9f;
        SC[tid] = sc;
      }
      __syncthreads();
      // softmax over 128 by wave 0
      if (tid < 64) {
        float m1 = fmaxf(SC[tid], SC[tid + 64]);
#pragma unroll
        for (int off = 32; off; off >>= 1) m1 = fmaxf(m1, __shfl_xor(m1, off));
        float e0 = __expf(SC[tid] - m1), e1 = __expf(SC[tid + 64] - m1);
        float ssum = e0 + e1;
#pragma unroll
        for (int off = 32; off; off >>= 1) ssum += __shfl_xor(ssum, off);
        float inv = 1.f / ssum;
        AT[tid] = e0 * inv;
        AT[tid + 64] = e1 * inv;
      }
      __syncthreads();
      // ctx (full 512, duplicated across quarters)
      {
        float c0 = 0.f, c1 = 0.f;
        const float* er = enc + (size_t)b * 512 + tid;
#pragma unroll 4
        for (int s = 0; s < 128; ++s) {
          float a = AT[s];
          c0 = fmaf(a, er[0], c0);
          c1 = fmaf(a, er[256], c1);
          er += 32 * 512;
        }
        CTX[tid] = c0;
        CTX[tid + 256] = c1;
      }
      __syncthreads();
      // concat: this quarter's 128 outputs, 2 threads per g (k-split over [ctx|x])
      {
        const int gg = tid >> 1, kh = tid & 1;
        const int g = q * 128 + gg;
        const float* wrow = Wc + (size_t)g * 1024 + kh * 512;
        const float* src = kh ? X : CTX;
        float a = 0.f;
#pragma unroll 4
        for (int k = 0; k < 512; k += 4)
          a += dot4(*(const float4*)(wrow + k), *(const float4*)(src + k));
        PART[tid] = a;
      }
      __syncthreads();
      if (tid < 128) {
        const int g = q * 128 + tid;
        float vv = tanhfast(PART[2 * tid] + PART[2 * tid + 1] + bc[g]);
        cbf[((size_t)t * 32 + b) * 512 + g] = f2bf(vv);
      }
    } else {
      if (t < 31) {
        const int base = (bid - 128) * 384;
        gh0_one(base + tid, h0b + nxt * 16384, Whh, bhh, gh0v);
        if (tid < 128) gh0_one(base + 256 + tid, h0b + nxt * 16384, Whh, bhh, gh0v);
      } else {
        const int i = (bid - 128) * 256 + tid;
        if (i < 16384) out_hf[i] = h0b[0 * 16384 + i];  // nxt==0 at t=31
      }
    }
    if (t < 31) gridbar(bar);
  }
}

// ---------------- bf16 MFMA vocab projection: C[1024,V] = concat * Ws^T + bs ---------
__global__ __launch_bounds__(256) void proj_kernel(const unsigned short* __restrict__ A,
                                                   const unsigned short* __restrict__ Bw,
                                                   const float* __restrict__ bs,
                                                   float* __restrict__ C) {
  __shared__ short8x AsV[512];  // 128 x 32 bf16
  __shared__ short8x BsV[512];
  short* As = (short*)AsV;
  short* Bs = (short*)BsV;
  const int tid = threadIdx.x;
  const int lane = tid & 63, wv = tid >> 6;
  const int m0 = blockIdx.x * 128;
  const int n0 = blockIdx.y * 128;
  const int wm = (wv >> 1) * 64, wn = (wv & 1) * 64;
  f32x4 acc[4][4] = {};
  const int sr = lane >> 2, sb = (lane & 3) * 8;
  const unsigned short* gA1 = A + (size_t)(m0 + wv * 16 + sr) * 512 + sb;
  const unsigned short* gA2 = gA1 + (size_t)64 * 512;
  const unsigned short* gB1 = Bw + (size_t)(n0 + wv * 16 + sr) * 512 + sb;
  const unsigned short* gB2 = gB1 + (size_t)64 * 512;
  short* lA1 = As + (wv * 16) * 32;
  short* lA2 = As + (64 + wv * 16) * 32;
  short* lB1 = Bs + (wv * 16) * 32;
  short* lB2 = Bs + (64 + wv * 16) * 32;
  const int rA = wm + (lane & 15);
  const int rB = wn + (lane & 15);
  const int kb = (lane >> 4) * 8;
  for (int kt = 0; kt < 16; ++kt) {
    const int ko = kt * 32;
    __syncthreads();
    async16(gA1 + ko, lA1);
    async16(gA2 + ko, lA2);
    async16(gB1 + ko, lB1);
    async16(gB2 + ko, lB2);
    __syncthreads();
    short8x af[4], bf[4];
#pragma unroll
    for (int i = 0; i < 4; ++i) af[i] = *(const short8x*)(As + (rA + i * 16) * 32 + kb);
#pragma unroll
    for (int i = 0; i < 4; ++i) bf[i] = *(const short8x*)(Bs + (rB + i * 16) * 32 + kb);
#pragma unroll
    for (int mo = 0; mo < 4; ++mo)
#pragma unroll
      for (int no = 0; no < 4; ++no)
        acc[mo][no] = __builtin_amdgcn_mfma_f32_16x16x32_bf16(af[mo], bf[no], acc[mo][no], 0, 0, 0);
  }
#pragma unroll
  for (int no = 0; no < 4; ++no) {
    const int col = n0 + wn + no * 16 + (lane & 15);
    if (col < V_) {
      const float bsv = bs[col];
#pragma unroll
      for (int mo = 0; mo < 4; ++mo) {
        const int row = m0 + wm + mo * 16 + ((lane >> 4) << 2);
        f32x4 v = acc[mo][no];
        C[(size_t)(row + 0) * V_ + col] = v[0] + bsv;
        C[(size_t)(row + 1) * V_ + col] = v[1] + bsv;
        C[(size_t)(row + 2) * V_ + col] = v[2] + bsv;
        C[(size_t)(row + 3) * V_ + col] = v[3] + bsv;
      }
    }
  }
}

extern "C" void kernel_launch(void* const* d_in, const int* in_sizes, int n_in,
                              void* d_out, int out_size, void* d_ws, size_t ws_size,
                              hipStream_t stream) {
  (void)in_sizes; (void)n_in; (void)out_size; (void)ws_size;
  const int* tgt = (const int*)d_in[0];
  const float* dh = (const float*)d_in[1];
  const float* enc = (const float*)d_in[2];
  const unsigned char* mask = (const unsigned char*)d_in[3];  // all-false bool; width-agnostic read
  const float* embW = (const float*)d_in[4];
  const float* Wih = (const float*)d_in[5];
  const float* Whh = (const float*)d_in[6];
  const float* bih = (const float*)d_in[7];
  const float* bhh = (const float*)d_in[8];
  const float* Wa = (const float*)d_in[9];
  const float* ba = (const float*)d_in[10];
  const float* Wc = (const float*)d_in[11];
  const float* bc = (const float*)d_in[12];
  const float* Ws = (const float*)d_in[13];
  const float* bs = (const float*)d_in[14];
  float* out = (float*)d_out;

  // workspace layout (~68.1 MB)
  char* w = (char*)d_ws;
  int* bar = (int*)w;                                  // 4096 B
  float* h0b = (float*)(w + 4096);                     // 2*16384
  float* h1b = h0b + 32768;                            // 2*16384
  float* gh0v = h1b + 32768;                           // 49152
  float* gx1v = gh0v + 49152;                          // 49152
  float* gh1v = gx1v + 49152;                          // 49152
  float* gx0v = gh1v + 49152;                          // 1024*1536
  float* encp = gx0v + 1572864;                        // 4096*512
  unsigned short* cbf = (unsigned short*)(encp + 2097152);  // 1024*512 bf16
  unsigned short* wsb = cbf + 524288;                  // VPAD*512 bf16

  hipMemsetAsync(bar, 0, 4096, stream);
  cvt_kernel<<<25152, 256, 0, stream>>>(Ws, wsb);
  gemm_f32<0><<<dim3(24, 16), 256, 0, stream>>>(embW, Wih, bih, gx0v, tgt, 1536);
  gemm_f32<1><<<dim3(8, 64), 256, 0, stream>>>(enc, Wa, ba, encp, nullptr, 512);
  seq_kernel<<<256, 256, 0, stream>>>(dh, enc, mask, Whh, Wih, bih, bhh, Wc, bc, bar,
                                      h0b, h1b, gh0v, gx1v, gh1v, gx0v, encp, cbf,
                                      out + (size_t)1024 * V_);
  proj_kernel<<<dim3(8, 393), 256, 0, stream>>>(cbf, wsb, bs, out);
}

// Round 2
// 2397.504 us; speedup vs baseline: 1.1977x; 1.1977x over previous
//
#include <hip/hip_runtime.h>
#include <hip/hip_bf16.h>
#include <stdint.h>
#include <stddef.h>

// Problem constants
#define B_ 32
#define T_ 32
#define S_ 128
#define H_ 512
#define V_ 50257
#define VPAD 50304
#define TH3 1536   // 3*H

typedef __attribute__((ext_vector_type(8))) short short8x;
typedef __attribute__((ext_vector_type(4))) float f32x4;

__device__ __forceinline__ float sigf(float x) { return 1.f / (1.f + __expf(-x)); }
__device__ __forceinline__ float tanhfast(float x) {
  float e = __expf(2.f * x);
  return 1.f - 2.f / (e + 1.f);
}
__device__ __forceinline__ unsigned short f2bf(float x) {
  unsigned int u = __float_as_uint(x);
  return (unsigned short)((u + 0x7fffu + ((u >> 16) & 1u)) >> 16);
}
__device__ __forceinline__ float dot4(float4 a, float4 b) {
  return a.x * b.x + a.y * b.y + a.z * b.z + a.w * b.w;
}

__device__ __forceinline__ void async16(const unsigned short* g, short* l) {
  __builtin_amdgcn_global_load_lds(
      (const __attribute__((address_space(1))) unsigned int*)g,
      (__attribute__((address_space(3))) unsigned int*)l, 16, 0, 0);
}

// ---------------- hierarchical grid barrier (256 blocks) ----------------
__device__ __forceinline__ void gridbar(int* bar) {
  __syncthreads();
  if (threadIdx.x == 0) {
    int* gen = bar + 512;
    int g = __hip_atomic_load(gen, __ATOMIC_RELAXED, __HIP_MEMORY_SCOPE_AGENT);
    int* c1 = bar + ((blockIdx.x >> 5) << 5);
    int a = __hip_atomic_fetch_add(c1, 1, __ATOMIC_ACQ_REL, __HIP_MEMORY_SCOPE_AGENT);
    bool done = false;
    if (a == 31) {
      __hip_atomic_store(c1, 0, __ATOMIC_RELAXED, __HIP_MEMORY_SCOPE_AGENT);
      int a2 = __hip_atomic_fetch_add(bar + 448, 1, __ATOMIC_ACQ_REL, __HIP_MEMORY_SCOPE_AGENT);
      if (a2 == 7) {
        __hip_atomic_store(bar + 448, 0, __ATOMIC_RELAXED, __HIP_MEMORY_SCOPE_AGENT);
        __hip_atomic_fetch_add(gen, 1, __ATOMIC_RELEASE, __HIP_MEMORY_SCOPE_AGENT);
        done = true;
      }
    }
    if (!done) {
      while (__hip_atomic_load(gen, __ATOMIC_RELAXED, __HIP_MEMORY_SCOPE_AGENT) == g)
        __builtin_amdgcn_s_sleep(1);
      __builtin_amdgcn_fence(__ATOMIC_ACQUIRE, "agent");
    }
  }
  __syncthreads();
}

// ---------------- Ws fp32 -> bf16 (padded to VPAD, pad rows zero) ----------------
__global__ __launch_bounds__(256) void cvt_kernel(const float* __restrict__ Ws,
                                                  unsigned short* __restrict__ outb) {
  size_t i = ((size_t)blockIdx.x * 256 + threadIdx.x) * 4;
  if (i >= (size_t)VPAD * 512) return;
  float4 f;
  if (i < (size_t)V_ * 512) f = *(const float4*)(Ws + i);
  else f = make_float4(0.f, 0.f, 0.f, 0.f);
  ushort4 u;
  u.x = f2bf(f.x); u.y = f2bf(f.y); u.z = f2bf(f.z); u.w = f2bf(f.w);
  *(ushort4*)(outb + i) = u;
}

// ---------------- generic fp32 tiled GEMM: C[M,N] = A[M,512] * Bw[N,512]^T + bias ----
template <int MODE>
__global__ __launch_bounds__(256) void gemm_f32(const float* __restrict__ Asrc,
                                                const float* __restrict__ Bw,
                                                const float* __restrict__ bias,
                                                float* __restrict__ Cout,
                                                const int* __restrict__ tgt, int N) {
  __shared__ __align__(16) float As[16][68];
  __shared__ __align__(16) float Bs[16][68];
  const int tid = threadIdx.x;
  const int tx = tid & 15, ty = tid >> 4;
  const int m0 = blockIdx.y * 64, n0 = blockIdx.x * 64;
  const int srow = tid >> 2, skq = (tid & 3) * 4;
  const float* arow;
  {
    int m = m0 + srow;
    if (MODE == 0) {
      int t = m >> 5, b = m & 31;
      int tok = (t == 0) ? 1 : tgt[b * 32 + t - 1];
      arow = Asrc + (size_t)tok * 512;
    } else {
      int b = m >> 7, s = m & 127;
      arow = Asrc + ((size_t)s * 32 + b) * 512;
    }
  }
  const float* brow = Bw + (size_t)(n0 + srow) * 512;
  float acc[4][4] = {};
  for (int k0 = 0; k0 < 512; k0 += 16) {
    float4 av = *(const float4*)(arow + k0 + skq);
    float4 bv = *(const float4*)(brow + k0 + skq);
    __syncthreads();
    As[skq + 0][srow] = av.x; As[skq + 1][srow] = av.y;
    As[skq + 2][srow] = av.z; As[skq + 3][srow] = av.w;
    Bs[skq + 0][srow] = bv.x; Bs[skq + 1][srow] = bv.y;
    Bs[skq + 2][srow] = bv.z; Bs[skq + 3][srow] = bv.w;
    __syncthreads();
#pragma unroll
    for (int kk = 0; kk < 16; ++kk) {
      float4 a4 = *(const float4*)&As[kk][ty * 4];
      float4 b4 = *(const float4*)&Bs[kk][tx * 4];
      acc[0][0] += a4.x * b4.x; acc[0][1] += a4.x * b4.y; acc[0][2] += a4.x * b4.z; acc[0][3] += a4.x * b4.w;
      acc[1][0] += a4.y * b4.x; acc[1][1] += a4.y * b4.y; acc[1][2] += a4.y * b4.z; acc[1][3] += a4.y * b4.w;
      acc[2][0] += a4.z * b4.x; acc[2][1] += a4.z * b4.y; acc[2][2] += a4.z * b4.z; acc[2][3] += a4.z * b4.w;
      acc[3][0] += a4.w * b4.x; acc[3][1] += a4.w * b4.y; acc[3][2] += a4.w * b4.z; acc[3][3] += a4.w * b4.w;
    }
  }
  float4 b4 = *(const float4*)(bias + n0 + tx * 4);
#pragma unroll
  for (int i = 0; i < 4; ++i) {
    float4 o;
    o.x = acc[i][0] + b4.x; o.y = acc[i][1] + b4.y;
    o.z = acc[i][2] + b4.z; o.w = acc[i][3] + b4.w;
    *(float4*)(Cout + (size_t)(m0 + ty * 4 + i) * N + n0 + tx * 4) = o;
  }
}

// ---------------- persistent pipelined sequential kernel ----------------
// 256 blocks x 256 threads, 1 grid barrier per phase, 36 phases (p = -1..34)
// roles: [0,64)   L0  : gh0(p+1)+cell0 -> x0(p+1)   (gate-triple rows of Whh0)
//        [64,192) L1  : gx1(p)+gh1(p)+cell1 -> x1(p)
//        [192,224)ATT-S: scores/softmax(p-1) -> attn ; CAT rows 0..255   (p-3)
//        [224,256)ATT-C: ctx(p-2)                    ; CAT rows 256..511 (p-3)
__global__ __launch_bounds__(256) void seq_kernel(
    const float* __restrict__ dh, const float* __restrict__ enc,
    const unsigned char* __restrict__ mask,
    const float* __restrict__ Whh, const float* __restrict__ Wih,
    const float* __restrict__ bih, const float* __restrict__ bhh,
    const float* __restrict__ Wc, const float* __restrict__ bc,
    const float* __restrict__ gx0v, const float* __restrict__ encp,
    int* __restrict__ bar, float* __restrict__ x0buf, float* __restrict__ x1buf,
    float* __restrict__ attnbuf, float* __restrict__ ctxbuf,
    unsigned short* __restrict__ cbf, float* __restrict__ out_hf) {
  const int tid = threadIdx.x, bid = blockIdx.x;
  __shared__ __align__(16) float sm[3456];
  const int lane = tid & 63, wv = tid >> 6;
  const int bb = lane & 31, rh = lane >> 5;  // lane = (batch, row-half)

  for (int p = -1; p <= 34; ++p) {
    if (bid < 64) {
      // ---------------- L0 ----------------
      if (p <= 30) {
        const int iset0 = bid * 8;
        const float* xsrc = (p == -1) ? dh : (x0buf + (p & 1) * 16384);
        float acc[12];
#pragma unroll
        for (int r = 0; r < 12; ++r) acc[r] = 0.f;
        const float* xb = xsrc + bb * 512 + wv * 128;
        for (int c = 0; c < 4; ++c) {
          float4 xv[8];
#pragma unroll
          for (int u = 0; u < 8; ++u) xv[u] = *(const float4*)(xb + c * 32 + u * 4);
#pragma unroll
          for (int rr = 0; rr < 12; ++rr) {
            const int rloc = rh * 12 + rr;
            const int g = rloc >> 3, ii = rloc & 7;  // local row = g*8+ii
            const float* wrow = Whh + (size_t)(g * 512 + iset0 + ii) * 512 + wv * 128 + c * 32;
#pragma unroll
            for (int u = 0; u < 8; ++u)
              acc[rr] += dot4(*(const float4*)(wrow + u * 4), xv[u]);
          }
        }
        __syncthreads();
#pragma unroll
        for (int rr = 0; rr < 12; ++rr)
          sm[wv * 768 + (rh * 12 + rr) * 32 + bb] = acc[rr];
        __syncthreads();
        {
          const int b2 = tid & 31, i2 = tid >> 5;  // i2 in [0,8)
          const int ig = iset0 + i2;
          float s0 = bhh[ig], s1 = bhh[512 + ig], s2 = bhh[1024 + ig];
#pragma unroll
          for (int w = 0; w < 4; ++w) {
            s0 += sm[w * 768 + (i2) * 32 + b2];
            s1 += sm[w * 768 + (8 + i2) * 32 + b2];
            s2 += sm[w * 768 + (16 + i2) * 32 + b2];
          }
          const float* gx = gx0v + ((size_t)(p + 1) * 32 + b2) * 1536;
          const float hv = xsrc[b2 * 512 + ig];
          const float r = sigf(gx[ig] + s0);
          const float z = sigf(gx[512 + ig] + s1);
          const float n = tanhfast(gx[1024 + ig] + r * s2);
          const float xn = (1.f - z) * n + z * hv;
          x0buf[((p + 1) & 1) * 16384 + b2 * 512 + ig] = xn;
          if (p == 30) out_hf[b2 * 512 + ig] = xn;
        }
      }
    } else if (bid < 192) {
      // ---------------- L1 ----------------
      if (p >= 0 && p <= 31) {
        const int iset0 = (bid - 64) * 4;
        const float* xs0 = x0buf + (p & 1) * 16384;
        const float* xs1 = (p == 0) ? (dh + 16384) : (x1buf + ((p - 1) & 3) * 16384);
        float acc[12];
#pragma unroll
        for (int r = 0; r < 12; ++r) acc[r] = 0.f;
        // pass 1: gx1 = Wih1 . x0(p)
        {
          const float* xb = xs0 + bb * 512 + wv * 128;
          for (int c = 0; c < 4; ++c) {
            float4 xv[8];
#pragma unroll
            for (int u = 0; u < 8; ++u) xv[u] = *(const float4*)(xb + c * 32 + u * 4);
#pragma unroll
            for (int rr = 0; rr < 6; ++rr) {
              const int rloc = rh * 6 + rr;
              const int g = rloc >> 2, ii = rloc & 3;  // local row = g*4+ii
              const float* wrow = Wih + (size_t)(1536 + g * 512 + iset0 + ii) * 512 + wv * 128 + c * 32;
#pragma unroll
              for (int u = 0; u < 8; ++u)
                acc[rr] += dot4(*(const float4*)(wrow + u * 4), xv[u]);
            }
          }
        }
        // pass 2: gh1 = Whh1 . x1(p-1)
        {
          const float* xb = xs1 + bb * 512 + wv * 128;
          for (int c = 0; c < 4; ++c) {
            float4 xv[8];
#pragma unroll
            for (int u = 0; u < 8; ++u) xv[u] = *(const float4*)(xb + c * 32 + u * 4);
#pragma unroll
            for (int rr = 0; rr < 6; ++rr) {
              const int rloc = rh * 6 + rr;
              const int g = rloc >> 2, ii = rloc & 3;
              const float* wrow = Whh + (size_t)(1536 + g * 512 + iset0 + ii) * 512 + wv * 128 + c * 32;
#pragma unroll
              for (int u = 0; u < 8; ++u)
                acc[6 + rr] += dot4(*(const float4*)(wrow + u * 4), xv[u]);
            }
          }
        }
        __syncthreads();
#pragma unroll
        for (int rr = 0; rr < 6; ++rr) {
          sm[wv * 768 + (rh * 6 + rr) * 32 + bb] = acc[rr];
          sm[wv * 768 + (12 + rh * 6 + rr) * 32 + bb] = acc[6 + rr];
        }
        __syncthreads();
        if (tid < 128) {
          const int b2 = tid & 31, i2 = tid >> 5;  // i2 in [0,4)
          const int ig = iset0 + i2;
          float gxs[3], ghs[3];
#pragma unroll
          for (int g = 0; g < 3; ++g) {
            float a = bih[1536 + g * 512 + ig];
            float h = bhh[1536 + g * 512 + ig];
#pragma unroll
            for (int w = 0; w < 4; ++w) {
              a += sm[w * 768 + (g * 4 + i2) * 32 + b2];
              h += sm[w * 768 + (12 + g * 4 + i2) * 32 + b2];
            }
            gxs[g] = a; ghs[g] = h;
          }
          const float hv = xs1[b2 * 512 + ig];
          const float r = sigf(gxs[0] + ghs[0]);
          const float z = sigf(gxs[1] + ghs[1]);
          const float n = tanhfast(gxs[2] + r * ghs[2]);
          const float xn = (1.f - z) * n + z * hv;
          x1buf[(p & 3) * 16384 + b2 * 512 + ig] = xn;
          if (p == 31) out_hf[16384 + b2 * 512 + ig] = xn;
        }
      }
    } else if (bid < 224) {
      // ---------------- ATT-S : scores + softmax for t = p-1 ----------------
      const int b = bid - 192;
      if (p >= 1 && p <= 32) {
        const int t = p - 1;
        const float* x1 = x1buf + (t & 3) * 16384 + b * 512;
        const int s = tid >> 1, kh = tid & 1;
        const float* ep = encp + ((size_t)b * 128 + s) * 512 + kh * 256;
        const float* xx = x1 + kh * 256;
        float a = 0.f;
#pragma unroll 8
        for (int k = 0; k < 256; k += 4)
          a += dot4(*(const float4*)(ep + k), *(const float4*)(xx + k));
        sm[tid] = a;
        __syncthreads();
        if (tid < 128) {
          float sc = sm[2 * tid] + sm[2 * tid + 1];
          if (mask[b * 128 + tid]) sc = -1e9f;
          sm[256 + tid] = sc;
        }
        __syncthreads();
        if (tid < 64) {
          float m1 = fmaxf(sm[256 + tid], sm[256 + tid + 64]);
#pragma unroll
          for (int off = 32; off; off >>= 1) m1 = fmaxf(m1, __shfl_xor(m1, off));
          float e0 = __expf(sm[256 + tid] - m1), e1 = __expf(sm[256 + tid + 64] - m1);
          float ssum = e0 + e1;
#pragma unroll
          for (int off = 32; off; off >>= 1) ssum += __shfl_xor(ssum, off);
          float inv = 1.f / ssum;
          sm[384 + tid] = e0 * inv;
          sm[384 + tid + 64] = e1 * inv;
        }
        __syncthreads();
        if (tid < 128) attnbuf[(t & 1) * 4096 + b * 128 + tid] = sm[384 + tid];
      }
      // CAT rows 0..255, t = p-3
      if (p >= 3) {
        const int t = p - 3;
        const int gg = (bid - 192) * 8 + (tid >> 5);
        const int b2 = tid & 31;
        const float* ctx = ctxbuf + (t & 1) * 16384 + b2 * 512;
        const float* x1c = x1buf + (t & 3) * 16384 + b2 * 512;
        const float* wr = Wc + (size_t)gg * 1024;
        float a = bc[gg];
#pragma unroll 4
        for (int k = 0; k < 512; k += 4) a += dot4(*(const float4*)(wr + k), *(const float4*)(ctx + k));
#pragma unroll 4
        for (int k = 0; k < 512; k += 4) a += dot4(*(const float4*)(wr + 512 + k), *(const float4*)(x1c + k));
        cbf[((size_t)t * 32 + b2) * 512 + gg] = f2bf(tanhfast(a));
      }
    } else {
      // ---------------- ATT-C : ctx for t = p-2 ----------------
      const int b = bid - 224;
      if (p >= 2 && p <= 33) {
        const int t = p - 2;
        if (tid < 128) sm[tid] = attnbuf[(t & 1) * 4096 + b * 128 + tid];
        __syncthreads();
        if (tid < 128) {
          const int h4 = tid * 4;
          float4 c = make_float4(0.f, 0.f, 0.f, 0.f);
          for (int s = 0; s < 128; ++s) {
            const float a = sm[s];
            const float4 e = *(const float4*)(enc + ((size_t)s * 32 + b) * 512 + h4);
            c.x += a * e.x; c.y += a * e.y; c.z += a * e.z; c.w += a * e.w;
          }
          *(float4*)(ctxbuf + (t & 1) * 16384 + b * 512 + h4) = c;
        }
        __syncthreads();
      }
      // CAT rows 256..511, t = p-3
      if (p >= 3) {
        const int t = p - 3;
        const int gg = 256 + (bid - 224) * 8 + (tid >> 5);
        const int b2 = tid & 31;
        const float* ctx = ctxbuf + (t & 1) * 16384 + b2 * 512;
        const float* x1c = x1buf + (t & 3) * 16384 + b2 * 512;
        const float* wr = Wc + (size_t)gg * 1024;
        float a = bc[gg];
#pragma unroll 4
        for (int k = 0; k < 512; k += 4) a += dot4(*(const float4*)(wr + k), *(const float4*)(ctx + k));
#pragma unroll 4
        for (int k = 0; k < 512; k += 4) a += dot4(*(const float4*)(wr + 512 + k), *(const float4*)(x1c + k));
        cbf[((size_t)t * 32 + b2) * 512 + gg] = f2bf(tanhfast(a));
      }
    }
    if (p < 34) gridbar(bar);
  }
}

// ---------------- bf16 MFMA vocab projection: C[1024,V] = concat * Ws^T + bs ---------
__global__ __launch_bounds__(256) void proj_kernel(const unsigned short* __restrict__ A,
                                                   const unsigned short* __restrict__ Bw,
                                                   const float* __restrict__ bs,
                                                   float* __restrict__ C) {
  __shared__ short8x AsV[512];
  __shared__ short8x BsV[512];
  short* As = (short*)AsV;
  short* Bs = (short*)BsV;
  const int tid = threadIdx.x;
  const int lane = tid & 63, wv = tid >> 6;
  const int m0 = blockIdx.x * 128;
  const int n0 = blockIdx.y * 128;
  const int wm = (wv >> 1) * 64, wn = (wv & 1) * 64;
  f32x4 acc[4][4] = {};
  const int sr = lane >> 2, sb = (lane & 3) * 8;
  const unsigned short* gA1 = A + (size_t)(m0 + wv * 16 + sr) * 512 + sb;
  const unsigned short* gA2 = gA1 + (size_t)64 * 512;
  const unsigned short* gB1 = Bw + (size_t)(n0 + wv * 16 + sr) * 512 + sb;
  const unsigned short* gB2 = gB1 + (size_t)64 * 512;
  short* lA1 = As + (wv * 16) * 32;
  short* lA2 = As + (64 + wv * 16) * 32;
  short* lB1 = Bs + (wv * 16) * 32;
  short* lB2 = Bs + (64 + wv * 16) * 32;
  const int rA = wm + (lane & 15);
  const int rB = wn + (lane & 15);
  const int kb = (lane >> 4) * 8;
  for (int kt = 0; kt < 16; ++kt) {
    const int ko = kt * 32;
    __syncthreads();
    async16(gA1 + ko, lA1);
    async16(gA2 + ko, lA2);
    async16(gB1 + ko, lB1);
    async16(gB2 + ko, lB2);
    __syncthreads();
    short8x af[4], bf[4];
#pragma unroll
    for (int i = 0; i < 4; ++i) af[i] = *(const short8x*)(As + (rA + i * 16) * 32 + kb);
#pragma unroll
    for (int i = 0; i < 4; ++i) bf[i] = *(const short8x*)(Bs + (rB + i * 16) * 32 + kb);
#pragma unroll
    for (int mo = 0; mo < 4; ++mo)
#pragma unroll
      for (int no = 0; no < 4; ++no)
        acc[mo][no] = __builtin_amdgcn_mfma_f32_16x16x32_bf16(af[mo], bf[no], acc[mo][no], 0, 0, 0);
  }
#pragma unroll
  for (int no = 0; no < 4; ++no) {
    const int col = n0 + wn + no * 16 + (lane & 15);
    if (col < V_) {
      const float bsv = bs[col];
#pragma unroll
      for (int mo = 0; mo < 4; ++mo) {
        const int row = m0 + wm + mo * 16 + ((lane >> 4) << 2);
        f32x4 v = acc[mo][no];
        C[(size_t)(row + 0) * V_ + col] = v[0] + bsv;
        C[(size_t)(row + 1) * V_ + col] = v[1] + bsv;
        C[(size_t)(row + 2) * V_ + col] = v[2] + bsv;
        C[(size_t)(row + 3) * V_ + col] = v[3] + bsv;
      }
    }
  }
}

extern "C" void kernel_launch(void* const* d_in, const int* in_sizes, int n_in,
                              void* d_out, int out_size, void* d_ws, size_t ws_size,
                              hipStream_t stream) {
  (void)in_sizes; (void)n_in; (void)out_size; (void)ws_size;
  const int* tgt = (const int*)d_in[0];
  const float* dh = (const float*)d_in[1];
  const float* enc = (const float*)d_in[2];
  const unsigned char* mask = (const unsigned char*)d_in[3];
  const float* embW = (const float*)d_in[4];
  const float* Wih = (const float*)d_in[5];
  const float* Whh = (const float*)d_in[6];
  const float* bih = (const float*)d_in[7];
  const float* bhh = (const float*)d_in[8];
  const float* Wa = (const float*)d_in[9];
  const float* ba = (const float*)d_in[10];
  const float* Wc = (const float*)d_in[11];
  const float* bc = (const float*)d_in[12];
  const float* Ws = (const float*)d_in[13];
  const float* bs = (const float*)d_in[14];
  float* out = (float*)d_out;

  // workspace layout (~67.8 MB)
  char* w = (char*)d_ws;
  int* bar = (int*)w;                                   // 4096 B
  float* x0buf = (float*)(w + 4096);                    // 2*16384 f
  float* x1buf = x0buf + 32768;                         // 4*16384 f
  float* attnbuf = x1buf + 65536;                       // 2*32*128 f
  float* ctxbuf = attnbuf + 8192;                       // 2*16384 f
  float* gx0v = ctxbuf + 32768;                         // 1024*1536 f
  float* encp = gx0v + 1572864;                         // 4096*512 f
  unsigned short* cbf = (unsigned short*)(encp + 2097152);  // 1024*512 bf16
  unsigned short* wsb = cbf + 524288;                   // VPAD*512 bf16

  hipMemsetAsync(bar, 0, 4096, stream);
  cvt_kernel<<<25152, 256, 0, stream>>>(Ws, wsb);
  gemm_f32<0><<<dim3(24, 16), 256, 0, stream>>>(embW, Wih, bih, gx0v, tgt, 1536);
  gemm_f32<1><<<dim3(8, 64), 256, 0, stream>>>(enc, Wa, ba, encp, nullptr, 512);
  seq_kernel<<<256, 256, 0, stream>>>(dh, enc, mask, Whh, Wih, bih, bhh, Wc, bc,
                                      gx0v, encp, bar, x0buf, x1buf, attnbuf, ctxbuf,
                                      cbf, out + (size_t)1024 * V_);
  proj_kernel<<<dim3(8, 393), 256, 0, stream>>>(cbf, wsb, bs, out);
}